// Round 1
// baseline (452.375 us; speedup 1.0000x reference)
//
#include <hip/hip_runtime.h>

// GGN fused kernel, fp32 baseline.
// Reference:
//   xi = x[i]
//   h1 = relu([x, xi] @ W_n2e.T + b_n2e)      -> fold xi-half into c1
//   h2 = relu(h1 @ W_e2e.T + b_e2e)
//   g  = sum_n adj[n] * h2[n]                 (256-vector)
//   h  = W_e2n @ g + b_e2n
//   out = xi + b_out + W_out @ [xi; h]

#define DIM 128
#define HID 256
#define BM 32
#define KC 16
#define THREADS 256

// ---------------- prep: c1[o] = b_n2e[o] + dot(W_n2e[o][128:256], xi) ------
__global__ void prep_kernel(const float* __restrict__ x,
                            const int* __restrict__ ip,
                            const float* __restrict__ W_n2e,
                            const float* __restrict__ b_n2e,
                            float* __restrict__ c1) {
    int o = blockIdx.x;          // 0..255
    int lane = threadIdx.x;      // 0..63
    const float* xi = x + (size_t)(*ip) * DIM;
    const float* wr = W_n2e + (size_t)o * (2 * DIM) + DIM;
    float s = wr[lane] * xi[lane] + wr[lane + 64] * xi[lane + 64];
    #pragma unroll
    for (int off = 32; off > 0; off >>= 1) s += __shfl_down(s, off);
    if (lane == 0) c1[o] = s + b_n2e[o];
}

// ---------------- main: per 32-node tile, fused GEMM1+relu+GEMM2+relu+reduce
__global__ __launch_bounds__(THREADS, 2)
void main_kernel(const float* __restrict__ x,
                 const float* __restrict__ adj,
                 const float* __restrict__ W1,   // W_n2e [256][256]
                 const float* __restrict__ W2,   // W_e2e [256][256]
                 const float* __restrict__ b2,   // b_e2e [256]
                 const float* __restrict__ c1,   // [256] in ws
                 float* __restrict__ P,          // [nb][256] partials in ws
                 int nb, int n_nodes) {
    __shared__ float xs[BM][DIM + 4];    // 32x132 fp32 = 16.9 KB
    __shared__ float h1s[BM][HID + 4];   // 32x260 fp32 = 33.3 KB
    __shared__ float Ws[KC][HID];        // 16x256 fp32 = 16.4 KB (k-chunk, transposed)

    const int t  = threadIdx.x;
    const int to = t & 31;       // output group: 8 outputs
    const int tm = t >> 5;       // node group: 4 nodes
    const int ob = to * 8;
    const int mb = tm * 4;

    float spart[8];
    #pragma unroll
    for (int q = 0; q < 8; ++q) spart[q] = 0.f;

    const int ntiles = n_nodes / BM;

    for (int tile = blockIdx.x; tile < ntiles; tile += nb) {
        // ---- stage x tile: 32x128 floats, coalesced float4 ----
        {
            const float4* src = (const float4*)(x + (size_t)tile * BM * DIM);
            #pragma unroll
            for (int j = 0; j < 4; ++j) {
                int f = t + j * THREADS;       // float4 id, 0..1023
                int r = f >> 5;                // row (128 floats = 32 float4/row)
                int c = (f & 31) << 2;
                *(float4*)&xs[r][c] = src[f];
            }
        }

        // ---- phase 1: h1 = relu(xs @ W1[:, :128]^T + c1) ----
        float acc[4][8];
        #pragma unroll
        for (int mi = 0; mi < 4; ++mi)
            #pragma unroll
            for (int oi = 0; oi < 8; ++oi) acc[mi][oi] = 0.f;

        for (int kc = 0; kc < DIM; kc += KC) {
            __syncthreads();   // prev chunk readers done; xs visible (1st iter)
            {   // stage W1 rows, transposed: Ws[kk][o]
                const float* wr = W1 + (size_t)t * (2 * DIM) + kc;
                float4 a = *(const float4*)(wr);
                float4 b = *(const float4*)(wr + 4);
                float4 c = *(const float4*)(wr + 8);
                float4 d = *(const float4*)(wr + 12);
                Ws[0][t] = a.x;  Ws[1][t] = a.y;  Ws[2][t] = a.z;  Ws[3][t] = a.w;
                Ws[4][t] = b.x;  Ws[5][t] = b.y;  Ws[6][t] = b.z;  Ws[7][t] = b.w;
                Ws[8][t] = c.x;  Ws[9][t] = c.y;  Ws[10][t] = c.z; Ws[11][t] = c.w;
                Ws[12][t] = d.x; Ws[13][t] = d.y; Ws[14][t] = d.z; Ws[15][t] = d.w;
            }
            __syncthreads();
            #pragma unroll
            for (int kk = 0; kk < KC; ++kk) {
                float4 w0 = *(const float4*)&Ws[kk][ob];
                float4 w1 = *(const float4*)&Ws[kk][ob + 4];
                float wv[8] = {w0.x, w0.y, w0.z, w0.w, w1.x, w1.y, w1.z, w1.w};
                float av[4];
                #pragma unroll
                for (int mi = 0; mi < 4; ++mi) av[mi] = xs[mb + mi][kc + kk];
                #pragma unroll
                for (int mi = 0; mi < 4; ++mi)
                    #pragma unroll
                    for (int oi = 0; oi < 8; ++oi)
                        acc[mi][oi] += av[mi] * wv[oi];
            }
        }

        // epilogue 1: + c1, relu, store h1s
        {
            float4 ca = *(const float4*)&c1[ob];
            float4 cb = *(const float4*)&c1[ob + 4];
            float cv[8] = {ca.x, ca.y, ca.z, ca.w, cb.x, cb.y, cb.z, cb.w};
            #pragma unroll
            for (int mi = 0; mi < 4; ++mi) {
                float4 u, v;
                u.x = fmaxf(acc[mi][0] + cv[0], 0.f);
                u.y = fmaxf(acc[mi][1] + cv[1], 0.f);
                u.z = fmaxf(acc[mi][2] + cv[2], 0.f);
                u.w = fmaxf(acc[mi][3] + cv[3], 0.f);
                v.x = fmaxf(acc[mi][4] + cv[4], 0.f);
                v.y = fmaxf(acc[mi][5] + cv[5], 0.f);
                v.z = fmaxf(acc[mi][6] + cv[6], 0.f);
                v.w = fmaxf(acc[mi][7] + cv[7], 0.f);
                *(float4*)&h1s[mb + mi][ob] = u;
                *(float4*)&h1s[mb + mi][ob + 4] = v;
            }
        }

        // ---- phase 2: acc2 = h1s @ W2^T ----
        float acc2[4][8];
        #pragma unroll
        for (int mi = 0; mi < 4; ++mi)
            #pragma unroll
            for (int oi = 0; oi < 8; ++oi) acc2[mi][oi] = 0.f;

        for (int kc = 0; kc < HID; kc += KC) {
            __syncthreads();   // prev chunk readers done; h1s visible (1st iter)
            {
                const float* wr = W2 + (size_t)t * HID + kc;
                float4 a = *(const float4*)(wr);
                float4 b = *(const float4*)(wr + 4);
                float4 c = *(const float4*)(wr + 8);
                float4 d = *(const float4*)(wr + 12);
                Ws[0][t] = a.x;  Ws[1][t] = a.y;  Ws[2][t] = a.z;  Ws[3][t] = a.w;
                Ws[4][t] = b.x;  Ws[5][t] = b.y;  Ws[6][t] = b.z;  Ws[7][t] = b.w;
                Ws[8][t] = c.x;  Ws[9][t] = c.y;  Ws[10][t] = c.z; Ws[11][t] = c.w;
                Ws[12][t] = d.x; Ws[13][t] = d.y; Ws[14][t] = d.z; Ws[15][t] = d.w;
            }
            __syncthreads();
            #pragma unroll
            for (int kk = 0; kk < KC; ++kk) {
                float4 w0 = *(const float4*)&Ws[kk][ob];
                float4 w1 = *(const float4*)&Ws[kk][ob + 4];
                float wv[8] = {w0.x, w0.y, w0.z, w0.w, w1.x, w1.y, w1.z, w1.w};
                float av[4];
                #pragma unroll
                for (int mi = 0; mi < 4; ++mi) av[mi] = h1s[mb + mi][kc + kk];
                #pragma unroll
                for (int mi = 0; mi < 4; ++mi)
                    #pragma unroll
                    for (int oi = 0; oi < 8; ++oi)
                        acc2[mi][oi] += av[mi] * wv[oi];
            }
        }

        // epilogue 2: + b2, relu, * adj, accumulate into spart
        {
            float4 ba = *(const float4*)&b2[ob];
            float4 bb = *(const float4*)&b2[ob + 4];
            float bv[8] = {ba.x, ba.y, ba.z, ba.w, bb.x, bb.y, bb.z, bb.w};
            #pragma unroll
            for (int mi = 0; mi < 4; ++mi) {
                float am = adj[tile * BM + mb + mi];
                #pragma unroll
                for (int oi = 0; oi < 8; ++oi) {
                    float v = fmaxf(acc2[mi][oi] + bv[oi], 0.f);
                    spart[oi] += v * am;
                }
            }
        }
    }

    // ---- block-level reduce of spart across the 8 tm-groups (reuse xs) ----
    __syncthreads();
    float* part = &xs[0][0];    // 8*256 = 2048 floats, xs holds 4224
    #pragma unroll
    for (int oi = 0; oi < 8; ++oi) part[tm * HID + ob + oi] = spart[oi];
    __syncthreads();
    float s = 0.f;
    #pragma unroll
    for (int g = 0; g < 8; ++g) s += part[g * HID + t];
    P[(size_t)blockIdx.x * HID + t] = s;
}

// ---------------- tail: g = sum_b P[b]; h = W_e2n@g + b; out = xi + W_out@[xi;h] + b_out
__global__ void tail_kernel(const float* __restrict__ x,
                            const int* __restrict__ ip,
                            const float* __restrict__ P, int nb,
                            const float* __restrict__ W_e2n,
                            const float* __restrict__ b_e2n,
                            const float* __restrict__ W_out,
                            const float* __restrict__ b_out,
                            float* __restrict__ out) {
    __shared__ float gs[HID];
    __shared__ float hs[HID];
    __shared__ float xis[DIM];
    int t = threadIdx.x;   // 0..255
    const float* xi = x + (size_t)(*ip) * DIM;
    if (t < DIM) xis[t] = xi[t];
    float s = 0.f;
    #pragma unroll 8
    for (int b = 0; b < nb; ++b) s += P[(size_t)b * HID + t];
    gs[t] = s;
    __syncthreads();
    {   // h = W_e2n @ g + b_e2n
        const float* wr = W_e2n + (size_t)t * HID;
        float h = b_e2n[t];
        #pragma unroll 8
        for (int k = 0; k < HID; ++k) h += wr[k] * gs[k];
        hs[t] = h;
    }
    __syncthreads();
    if (t < DIM) {
        const float* wo = W_out + (size_t)t * (DIM + HID);
        float v = b_out[t];
        #pragma unroll 8
        for (int k = 0; k < DIM; ++k) v += wo[k] * xis[k];
        #pragma unroll 8
        for (int k = 0; k < HID; ++k) v += wo[DIM + k] * hs[k];
        out[t] = xis[t] + v;
    }
}

extern "C" void kernel_launch(void* const* d_in, const int* in_sizes, int n_in,
                              void* d_out, int out_size, void* d_ws, size_t ws_size,
                              hipStream_t stream) {
    const float* x     = (const float*)d_in[0];
    const float* adj   = (const float*)d_in[1];
    const int*   ip    = (const int*)d_in[2];
    const float* W_n2e = (const float*)d_in[3];
    const float* b_n2e = (const float*)d_in[4];
    const float* W_e2e = (const float*)d_in[5];
    const float* b_e2e = (const float*)d_in[6];
    const float* W_e2n = (const float*)d_in[7];
    const float* b_e2n = (const float*)d_in[8];
    const float* W_out = (const float*)d_in[9];
    const float* b_out = (const float*)d_in[10];
    float* out = (float*)d_out;

    const int n_nodes = in_sizes[1];   // adj_col length = N

    float* c1 = (float*)d_ws;
    float* P  = c1 + HID;

    int nb = 512;
    while (nb > 8 && (size_t)(HID + nb * HID) * sizeof(float) > ws_size) nb >>= 1;

    prep_kernel<<<HID, 64, 0, stream>>>(x, ip, W_n2e, b_n2e, c1);
    main_kernel<<<nb, THREADS, 0, stream>>>(x, adj, W_n2e, W_e2e, b_e2e, c1, P,
                                            nb, n_nodes);
    tail_kernel<<<1, HID, 0, stream>>>(x, ip, P, nb, W_e2n, b_e2n, W_out, b_out, out);
}

// Round 2
// 405.527 us; speedup vs baseline: 1.1155x; 1.1155x over previous
//
#include <hip/hip_runtime.h>

// GGN fused kernel, fp32, SGPR-weight scheme.
//   xi = x[i]
//   h1 = relu([x, xi] @ W_n2e.T + b_n2e)   -> xi-half folded into c1
//   h2 = relu(h1 @ W_e2e.T + b_e2e)
//   g  = sum_n adj[n] * h2[n]
//   h  = W_e2n @ g + b_e2n
//   out = xi + b_out + W_out @ [xi; h]
//
// main_kernel: 1024 threads = 16 waves. lane = node (64-node tile),
// wave = 16 output columns (wave-uniform -> weights via s_load from
// pre-transposed W1t/W2t in ws). Per kk: 16 v_fmac (SGPR src) + 1 ds_read_b32.

#define DIM 128
#define HID 256
#define BM 64
#define TPB 1024

// ---------------- prep: c1[o] = b_n2e[o] + dot(W_n2e[o][128:256], xi) ------
__global__ void prep_c1(const float* __restrict__ x,
                        const int* __restrict__ ip,
                        const float* __restrict__ W_n2e,
                        const float* __restrict__ b_n2e,
                        float* __restrict__ c1) {
    int o = blockIdx.x;          // 0..255
    int lane = threadIdx.x;      // 0..63
    const float* xi = x + (size_t)(*ip) * DIM;
    const float* wr = W_n2e + (size_t)o * (2 * DIM) + DIM;
    float s = wr[lane] * xi[lane] + wr[lane + 64] * xi[lane + 64];
    #pragma unroll
    for (int off = 32; off > 0; off >>= 1) s += __shfl_down(s, off);
    if (lane == 0) c1[o] = s + b_n2e[o];
}

// ---------------- prep: transpose weights into ws --------------------------
// W1t[k][o] = W_n2e[o][k] (k<128), W2t[k][o] = W_e2e[o][k]
__global__ void prep_tr(const float* __restrict__ W_n2e,
                        const float* __restrict__ W_e2e,
                        float* __restrict__ W1t,
                        float* __restrict__ W2t) {
    int b = blockIdx.x;   // 0..383
    int t = threadIdx.x;  // 0..255 = output index o
    if (b < DIM) {
        W1t[(size_t)b * HID + t] = W_n2e[(size_t)t * (2 * DIM) + b];
    } else {
        int k = b - DIM;
        W2t[(size_t)k * HID + t] = W_e2e[(size_t)t * HID + k];
    }
}

// ---------------- main ------------------------------------------------------
__global__ __launch_bounds__(TPB, 4)
void main_kernel(const float* __restrict__ x,
                 const float* __restrict__ adj,
                 const float* __restrict__ W1t,   // [128][256] in ws
                 const float* __restrict__ W2t,   // [256][256] in ws
                 const float* __restrict__ c1,    // [256] in ws
                 const float* __restrict__ b2,    // b_e2e [256]
                 float* __restrict__ P,           // [nb][256] partials in ws
                 int n_nodes, int ntiles) {
    // union: phase1 x_T[128][65] (8320 floats) / phase2 h1_T[256][64] (16384)
    __shared__ float sm[16384];   // exactly 64 KiB

    const int t = threadIdx.x;
    const int lane = t & 63;                                   // node-in-tile
    const int w = __builtin_amdgcn_readfirstlane(t >> 6);      // wave id 0..15
    const int wbase = w * 16;                                  // 16 outputs

    // wave-uniform biases -> scalar regs
    float sc1[16], sb2[16];
    #pragma unroll
    for (int oi = 0; oi < 16; ++oi) {
        sc1[oi] = c1[wbase + oi];
        sb2[oi] = b2[wbase + oi];
    }

    float spart[16];
    #pragma unroll
    for (int oi = 0; oi < 16; ++oi) spart[oi] = 0.f;

    const float4* xg4 = (const float4*)x;

    for (int tile = blockIdx.x; tile < ntiles; tile += gridDim.x) {
        const int bn = tile * BM;

        __syncthreads();   // prev-tile G2 reads of h1 done before x overwrite
        // ---- stage x_T[k][node], pad 65 (2-way conflicts only) ----
        #pragma unroll
        for (int j = 0; j < 2; ++j) {
            int f = t + j * TPB;        // 0..2047 float4 ids (64 rows x 32)
            int r = f >> 5;             // node-in-tile
            int c4 = f & 31;            // float4 column
            int node = bn + r;
            float4 v = (node < n_nodes)
                         ? xg4[(size_t)node * (DIM / 4) + c4]
                         : make_float4(0.f, 0.f, 0.f, 0.f);
            int k0 = c4 * 4;
            sm[(k0 + 0) * 65 + r] = v.x;
            sm[(k0 + 1) * 65 + r] = v.y;
            sm[(k0 + 2) * 65 + r] = v.z;
            sm[(k0 + 3) * 65 + r] = v.w;
        }
        __syncthreads();

        // ---- G1: acc[oi] = sum_k x[node][k] * W1t[k][wbase+oi] ----
        float acc[16];
        #pragma unroll
        for (int oi = 0; oi < 16; ++oi) acc[oi] = 0.f;
        {
            const float* __restrict__ w1p = W1t + wbase;
            #pragma unroll 4
            for (int kk = 0; kk < DIM; ++kk) {
                float a = sm[kk * 65 + lane];
                const float* __restrict__ wp = w1p + (size_t)kk * HID;
                #pragma unroll
                for (int oi = 0; oi < 16; ++oi)
                    acc[oi] = fmaf(wp[oi], a, acc[oi]);
            }
        }
        float hv[16];
        #pragma unroll
        for (int oi = 0; oi < 16; ++oi) hv[oi] = fmaxf(acc[oi] + sc1[oi], 0.f);

        __syncthreads();   // all waves done reading x before h1 overwrites it
        #pragma unroll
        for (int oi = 0; oi < 16; ++oi)
            sm[(wbase + oi) * 64 + lane] = hv[oi];   // h1_T[o][node], 2-way
        __syncthreads();

        // ---- G2: acc2[oi] = sum_k h1[node][k] * W2t[k][wbase+oi] ----
        float av = (bn + lane < n_nodes) ? adj[bn + lane] : 0.f;
        float acc2[16];
        #pragma unroll
        for (int oi = 0; oi < 16; ++oi) acc2[oi] = 0.f;
        {
            const float* __restrict__ w2p = W2t + wbase;
            #pragma unroll 4
            for (int kk = 0; kk < HID; ++kk) {
                float a = sm[kk * 64 + lane];
                const float* __restrict__ wp = w2p + (size_t)kk * HID;
                #pragma unroll
                for (int oi = 0; oi < 16; ++oi)
                    acc2[oi] = fmaf(wp[oi], a, acc2[oi]);
            }
        }
        #pragma unroll
        for (int oi = 0; oi < 16; ++oi)
            spart[oi] += fmaxf(acc2[oi] + sb2[oi], 0.f) * av;
    }

    // ---- reduce spart over the wave's 64 lanes (nodes), write P ----
    #pragma unroll
    for (int oi = 0; oi < 16; ++oi) {
        float s = spart[oi];
        #pragma unroll
        for (int off = 32; off > 0; off >>= 1) s += __shfl_down(s, off);
        if (lane == 0) P[(size_t)blockIdx.x * HID + wbase + oi] = s;
    }
}

// ---------------- tail1: Q[b][o] = sum of 'rows_per' P rows -----------------
__global__ void tail1(const float* __restrict__ P, float* __restrict__ Q,
                      int rows_per) {
    int b = blockIdx.x;    // 0..63
    int t = threadIdx.x;   // 0..255
    float s = 0.f;
    for (int j = 0; j < rows_per; ++j)
        s += P[(size_t)(b * rows_per + j) * HID + t];
    Q[(size_t)b * HID + t] = s;
}

// ---------------- tail2: g -> h -> out --------------------------------------
__global__ void tail2(const float* __restrict__ x,
                      const int* __restrict__ ip,
                      const float* __restrict__ Q,
                      const float* __restrict__ W_e2n,
                      const float* __restrict__ b_e2n,
                      const float* __restrict__ W_out,
                      const float* __restrict__ b_out,
                      float* __restrict__ out) {
    __shared__ float gs[HID];
    __shared__ float hs[HID];
    __shared__ float xis[DIM];
    int t = threadIdx.x;   // 0..255
    const float* xi = x + (size_t)(*ip) * DIM;
    if (t < DIM) xis[t] = xi[t];
    float s = 0.f;
    #pragma unroll 8
    for (int b = 0; b < 64; ++b) s += Q[(size_t)b * HID + t];
    gs[t] = s;
    __syncthreads();
    {
        const float* wr = W_e2n + (size_t)t * HID;
        float h = b_e2n[t];
        #pragma unroll 8
        for (int k = 0; k < HID; ++k) h = fmaf(wr[k], gs[k], h);
        hs[t] = h;
    }
    __syncthreads();
    if (t < DIM) {
        const float* wo = W_out + (size_t)t * (DIM + HID);
        float v = b_out[t];
        #pragma unroll 8
        for (int k = 0; k < DIM; ++k) v = fmaf(wo[k], xis[k], v);
        #pragma unroll 8
        for (int k = 0; k < HID; ++k) v = fmaf(wo[DIM + k], hs[k], v);
        out[t] = xis[t] + v;
    }
}

extern "C" void kernel_launch(void* const* d_in, const int* in_sizes, int n_in,
                              void* d_out, int out_size, void* d_ws, size_t ws_size,
                              hipStream_t stream) {
    const float* x     = (const float*)d_in[0];
    const float* adj   = (const float*)d_in[1];
    const int*   ip    = (const int*)d_in[2];
    const float* W_n2e = (const float*)d_in[3];
    const float* b_n2e = (const float*)d_in[4];
    const float* W_e2e = (const float*)d_in[5];
    const float* b_e2e = (const float*)d_in[6];
    const float* W_e2n = (const float*)d_in[7];
    const float* b_e2n = (const float*)d_in[8];
    const float* W_out = (const float*)d_in[9];
    const float* b_out = (const float*)d_in[10];
    float* out = (float*)d_out;

    const int n_nodes = in_sizes[1];                 // N = adj length
    const int ntiles  = (n_nodes + BM - 1) / BM;

    // ws layout (floats): c1[256] | W1t[128*256] | W2t[256*256] | Q[64*256] | P[nb*256]
    float* c1  = (float*)d_ws;
    float* W1t = c1 + HID;
    float* W2t = W1t + DIM * HID;
    float* Q   = W2t + HID * HID;
    float* P   = Q + 64 * HID;
    const size_t fixed_floats = (size_t)(HID + DIM * HID + HID * HID + 64 * HID);

    int nb = 512;
    while (nb > 64 && (fixed_floats + (size_t)nb * HID) * sizeof(float) > ws_size)
        nb >>= 1;

    prep_c1<<<HID, 64, 0, stream>>>(x, ip, W_n2e, b_n2e, c1);
    prep_tr<<<DIM + HID, HID, 0, stream>>>(W_n2e, W_e2e, W1t, W2t);
    main_kernel<<<nb, TPB, 0, stream>>>(x, adj, W1t, W2t, c1, b_e2e, P,
                                        n_nodes, ntiles);
    tail1<<<64, HID, 0, stream>>>(P, Q, nb / 64);
    tail2<<<1, HID, 0, stream>>>(x, ip, Q, W_e2n, b_e2n, W_out, b_out, out);
}

// Round 3
// 213.543 us; speedup vs baseline: 2.1184x; 1.8990x over previous
//
#include <hip/hip_runtime.h>

// GGN fused kernel — split-bf16 (3-term) MFMA version.
//   xi = x[i]
//   h1 = relu([x, xi] @ W_n2e.T + b_n2e)   -> xi-half folded into c1 (fp32)
//   h2 = relu(h1 @ W_e2e.T + b_e2e)
//   g  = sum_n adj[n] * h2[n]
//   h  = W_e2n @ g + b_e2n
//   out = xi + b_out + W_out @ [xi; h]
//
// GEMM1/GEMM2 via v_mfma_f32_16x16x32_bf16 with a = ah+al, b = bh+bl,
// acc += ah*bh + al*bh + ah*bl  (fp32 accumulation, rel err ~2^-16).

#define DIM 128
#define HID 256
#define BM 64
#define TPB 512

typedef float  f32x4 __attribute__((ext_vector_type(4)));
typedef short  s16x8 __attribute__((ext_vector_type(8)));

__device__ __forceinline__ unsigned short f2bf(float f) {
    unsigned u = __float_as_uint(f);
    return (unsigned short)((u + 0x7FFFu + ((u >> 16) & 1u)) >> 16);
}
__device__ __forceinline__ float bf2f(unsigned short h) {
    return __uint_as_float(((unsigned)h) << 16);
}

#define MFMA_BF16(acc, a, b) \
    asm volatile("v_mfma_f32_16x16x32_bf16 %0, %1, %2, %0" \
                 : "+v"(acc) : "v"(a), "v"(b))

// LDS layout (bytes)
#define XH_OFF   0        // X hi  [64][128] bf16 = 16384
#define XL_OFF   16384    // X lo
#define H1H_OFF  32768    // H1 hi [64][256] bf16 = 32768
#define H1L_OFF  65536    // H1 lo
#define ADJ_OFF  98304    // adj [64] f32 = 256
#define SM_BYTES 98560

// ---------------- prep: c1[o] = b_n2e[o] + dot(W_n2e[o][128:256], xi) ------
__global__ void prep_c1(const float* __restrict__ x,
                        const int* __restrict__ ip,
                        const float* __restrict__ W_n2e,
                        const float* __restrict__ b_n2e,
                        float* __restrict__ c1) {
    int o = blockIdx.x;          // 0..255
    int lane = threadIdx.x;      // 0..63
    const float* xi = x + (size_t)(*ip) * DIM;
    const float* wr = W_n2e + (size_t)o * (2 * DIM) + DIM;
    float s = wr[lane] * xi[lane] + wr[lane + 64] * xi[lane + 64];
    #pragma unroll
    for (int off = 32; off > 0; off >>= 1) s += __shfl_down(s, off);
    if (lane == 0) c1[o] = s + b_n2e[o];
}

// ---------------- prep: pack weights into MFMA B-fragment order, hi/lo -----
// B-frag for (ks, cb): lane l holds B[ks*32 + (l>>4)*8 + r][cb*16 + (l&15)],
// r=0..7 contiguous:  dst = ((ks*16+cb)*64 + l)*8 + r
__global__ void prep_pack(const float* __restrict__ Wn2e,
                          const float* __restrict__ We2e,
                          short* __restrict__ W1h, short* __restrict__ W1l,
                          short* __restrict__ W2h, short* __restrict__ W2l) {
    int tid = blockIdx.x * 256 + threadIdx.x;   // 0 .. 98303
    float w; int o, k; short *dh, *dl;
    if (tid < 32768) {            // W1: [o<256][k<128] from W_n2e[o][k]
        o = tid >> 7; k = tid & 127;
        w = Wn2e[(size_t)o * 256 + k];
        dh = W1h; dl = W1l;
    } else {                      // W2: [o<256][k<256] from W_e2e[o][k]
        int u = tid - 32768;
        o = u >> 8; k = u & 255;
        w = We2e[(size_t)o * 256 + k];
        dh = W2h; dl = W2l;
    }
    int ks = k >> 5, koff = k & 31;
    int lane = ((koff >> 3) << 4) | (o & 15);
    int cb = o >> 4;
    size_t dst = ((size_t)((ks * 16 + cb) * 64 + lane)) * 8 + (koff & 7);
    unsigned short h = f2bf(w);
    dh[dst] = (short)h;
    dl[dst] = (short)f2bf(w - bf2f(h));
}

// ---------------- main ------------------------------------------------------
__global__ __launch_bounds__(TPB, 1)
void main_kernel(const float* __restrict__ x,
                 const float* __restrict__ adj,
                 const short* __restrict__ W1h, const short* __restrict__ W1l,
                 const short* __restrict__ W2h, const short* __restrict__ W2l,
                 const float* __restrict__ c1, const float* __restrict__ b2,
                 float* __restrict__ P, int n_nodes, int ntiles) {
    __shared__ __attribute__((aligned(16))) unsigned char sm[SM_BYTES];

    const int t  = threadIdx.x;
    const int l  = t & 63;
    const int w  = __builtin_amdgcn_readfirstlane(t >> 6);  // wave 0..7
    const int lc = l & 15;    // col-in-frag (B/D) = row-in-frag (A)
    const int lg = l >> 4;    // k-subgroup

    // per-lane biases for this wave's two 16-col fragments
    float c1v[2], b2v[2];
    #pragma unroll
    for (int nf = 0; nf < 2; ++nf) {
        int col = w * 32 + nf * 16 + lc;
        c1v[nf] = c1[col];
        b2v[nf] = b2[col];
    }

    float spart[2] = {0.f, 0.f};
    const float4* xg4 = (const float4*)x;

    for (int tile = blockIdx.x; tile < ntiles; tile += gridDim.x) {
        const int bn = tile * BM;

        __syncthreads();   // bar0: prev-iter readers of X/adj done

        // ---- stage X tile -> hi/lo bf16 in LDS (XOR-swizzled rows) ----
        #pragma unroll
        for (int j = 0; j < 4; ++j) {
            int f  = t + j * TPB;        // 0..2047 float4 ids
            int r  = f >> 5;             // node-in-tile 0..63
            int c4 = f & 31;             // float4 column
            int node = bn + r;
            float4 v = (node < n_nodes) ? xg4[(size_t)node * 32 + c4]
                                        : make_float4(0.f, 0.f, 0.f, 0.f);
            unsigned short h0 = f2bf(v.x), h1 = f2bf(v.y),
                           h2 = f2bf(v.z), h3 = f2bf(v.w);
            uint2 hu, lu;
            hu.x = (unsigned)h0 | ((unsigned)h1 << 16);
            hu.y = (unsigned)h2 | ((unsigned)h3 << 16);
            lu.x = (unsigned)f2bf(v.x - bf2f(h0)) |
                   ((unsigned)f2bf(v.y - bf2f(h1)) << 16);
            lu.y = (unsigned)f2bf(v.z - bf2f(h2)) |
                   ((unsigned)f2bf(v.w - bf2f(h3)) << 16);
            int cb = (c4 * 8) ^ ((r & 7) << 4);
            *(uint2*)(sm + XH_OFF + r * 256 + cb) = hu;
            *(uint2*)(sm + XL_OFF + r * 256 + cb) = lu;
        }
        if (t < BM) {
            int node = bn + t;
            *(float*)(sm + ADJ_OFF + t * 4) = (node < n_nodes) ? adj[node] : 0.f;
        }
        __syncthreads();   // bar1: X/adj staged

        // ---- GEMM1: acc1 = X @ W1  (K=128, 4 k-steps) ----
        f32x4 acc1[4][2];
        #pragma unroll
        for (int mf = 0; mf < 4; ++mf)
            #pragma unroll
            for (int nf = 0; nf < 2; ++nf)
                acc1[mf][nf] = (f32x4){0.f, 0.f, 0.f, 0.f};

        #pragma unroll
        for (int ks = 0; ks < 4; ++ks) {
            s16x8 ah[4], al[4];
            #pragma unroll
            for (int mf = 0; mf < 4; ++mf) {
                int row = mf * 16 + lc;
                int cb = (ks * 64 + lg * 16) ^ ((row & 7) << 4);
                ah[mf] = *(const s16x8*)(sm + XH_OFF + row * 256 + cb);
                al[mf] = *(const s16x8*)(sm + XL_OFF + row * 256 + cb);
            }
            s16x8 bh[2], bl[2];
            #pragma unroll
            for (int nf = 0; nf < 2; ++nf) {
                size_t bidx = ((size_t)((ks * 16 + (w * 2 + nf)) * 64 + l)) * 8;
                bh[nf] = *(const s16x8*)(W1h + bidx);
                bl[nf] = *(const s16x8*)(W1l + bidx);
            }
            #pragma unroll
            for (int mf = 0; mf < 4; ++mf)
                #pragma unroll
                for (int nf = 0; nf < 2; ++nf) {
                    MFMA_BF16(acc1[mf][nf], ah[mf], bh[nf]);
                    MFMA_BF16(acc1[mf][nf], al[mf], bh[nf]);
                    MFMA_BF16(acc1[mf][nf], ah[mf], bl[nf]);
                }
        }

        __syncthreads();   // bar2: all waves done reading X (and prev H1 reads long done)
        asm volatile("s_nop 7\n\ts_nop 7\n\ts_nop 7" ::: );

        // ---- epilogue1: +c1, relu, cvt hi/lo, store H1 (swizzled) ----
        #pragma unroll
        for (int mf = 0; mf < 4; ++mf)
            #pragma unroll
            for (int nf = 0; nf < 2; ++nf) {
                int col = w * 32 + nf * 16 + lc;
                #pragma unroll
                for (int r = 0; r < 4; ++r) {
                    int row = mf * 16 + lg * 4 + r;
                    float v = fmaxf(acc1[mf][nf][r] + c1v[nf], 0.f);
                    unsigned short h = f2bf(v);
                    unsigned short lo = f2bf(v - bf2f(h));
                    int cb = (col * 2) ^ ((row & 7) << 4);
                    *(unsigned short*)(sm + H1H_OFF + row * 512 + cb) = h;
                    *(unsigned short*)(sm + H1L_OFF + row * 512 + cb) = lo;
                }
            }
        __syncthreads();   // bar3: H1 visible to all waves

        // ---- GEMM2: acc2 = H1 @ W2  (K=256, 8 k-steps) ----
        f32x4 acc2[4][2];
        #pragma unroll
        for (int mf = 0; mf < 4; ++mf)
            #pragma unroll
            for (int nf = 0; nf < 2; ++nf)
                acc2[mf][nf] = (f32x4){0.f, 0.f, 0.f, 0.f};

        #pragma unroll
        for (int ks = 0; ks < 8; ++ks) {
            s16x8 ah[4], al[4];
            #pragma unroll
            for (int mf = 0; mf < 4; ++mf) {
                int row = mf * 16 + lc;
                int cb = (ks * 64 + lg * 16) ^ ((row & 7) << 4);
                ah[mf] = *(const s16x8*)(sm + H1H_OFF + row * 512 + cb);
                al[mf] = *(const s16x8*)(sm + H1L_OFF + row * 512 + cb);
            }
            s16x8 bh[2], bl[2];
            #pragma unroll
            for (int nf = 0; nf < 2; ++nf) {
                size_t bidx = ((size_t)((ks * 16 + (w * 2 + nf)) * 64 + l)) * 8;
                bh[nf] = *(const s16x8*)(W2h + bidx);
                bl[nf] = *(const s16x8*)(W2l + bidx);
            }
            #pragma unroll
            for (int mf = 0; mf < 4; ++mf)
                #pragma unroll
                for (int nf = 0; nf < 2; ++nf) {
                    MFMA_BF16(acc2[mf][nf], ah[mf], bh[nf]);
                    MFMA_BF16(acc2[mf][nf], al[mf], bh[nf]);
                    MFMA_BF16(acc2[mf][nf], ah[mf], bl[nf]);
                }
        }

        asm volatile("s_nop 7\n\ts_nop 7\n\ts_nop 7" ::: );

        // ---- epilogue2: +b2, relu, * adj[row], accumulate g-partials ----
        #pragma unroll
        for (int mf = 0; mf < 4; ++mf)
            #pragma unroll
            for (int r = 0; r < 4; ++r) {
                int row = mf * 16 + lg * 4 + r;
                float adv = *(const float*)(sm + ADJ_OFF + row * 4);
                #pragma unroll
                for (int nf = 0; nf < 2; ++nf)
                    spart[nf] += fmaxf(acc2[mf][nf][r] + b2v[nf], 0.f) * adv;
            }
    }

    // ---- reduce g-partials across the 4 row-subgroups, write P ----
    #pragma unroll
    for (int nf = 0; nf < 2; ++nf) {
        float s = spart[nf];
        s += __shfl_xor(s, 16);
        s += __shfl_xor(s, 32);
        if (l < 16)
            P[(size_t)blockIdx.x * HID + w * 32 + nf * 16 + l] = s;
    }
}

// ---------------- tail1: Q[b][o] = sum of 'rows_per' P rows -----------------
__global__ void tail1(const float* __restrict__ P, float* __restrict__ Q,
                      int rows_per) {
    int b = blockIdx.x;    // 0..63
    int t = threadIdx.x;   // 0..255
    float s = 0.f;
    for (int j = 0; j < rows_per; ++j)
        s += P[(size_t)(b * rows_per + j) * HID + t];
    Q[(size_t)b * HID + t] = s;
}

// ---------------- tail2: g -> h -> out --------------------------------------
__global__ void tail2(const float* __restrict__ x,
                      const int* __restrict__ ip,
                      const float* __restrict__ Q,
                      const float* __restrict__ W_e2n,
                      const float* __restrict__ b_e2n,
                      const float* __restrict__ W_out,
                      const float* __restrict__ b_out,
                      float* __restrict__ out) {
    __shared__ float gs[HID];
    __shared__ float hs[HID];
    __shared__ float xis[DIM];
    int t = threadIdx.x;   // 0..255
    const float* xi = x + (size_t)(*ip) * DIM;
    if (t < DIM) xis[t] = xi[t];
    float s = 0.f;
    #pragma unroll 8
    for (int b = 0; b < 64; ++b) s += Q[(size_t)b * HID + t];
    gs[t] = s;
    __syncthreads();
    {
        const float* wr = W_e2n + (size_t)t * HID;
        float h = b_e2n[t];
        #pragma unroll 8
        for (int k = 0; k < HID; ++k) h = fmaf(wr[k], gs[k], h);
        hs[t] = h;
    }
    __syncthreads();
    if (t < DIM) {
        const float* wo = W_out + (size_t)t * (DIM + HID);
        float v = b_out[t];
        #pragma unroll 8
        for (int k = 0; k < DIM; ++k) v = fmaf(wo[k], xis[k], v);
        #pragma unroll 8
        for (int k = 0; k < HID; ++k) v = fmaf(wo[DIM + k], hs[k], v);
        out[t] = xis[t] + v;
    }
}

extern "C" void kernel_launch(void* const* d_in, const int* in_sizes, int n_in,
                              void* d_out, int out_size, void* d_ws, size_t ws_size,
                              hipStream_t stream) {
    const float* x     = (const float*)d_in[0];
    const float* adj   = (const float*)d_in[1];
    const int*   ip    = (const int*)d_in[2];
    const float* W_n2e = (const float*)d_in[3];
    const float* b_n2e = (const float*)d_in[4];
    const float* W_e2e = (const float*)d_in[5];
    const float* b_e2e = (const float*)d_in[6];
    const float* W_e2n = (const float*)d_in[7];
    const float* b_e2n = (const float*)d_in[8];
    const float* W_out = (const float*)d_in[9];
    const float* b_out = (const float*)d_in[10];
    float* out = (float*)d_out;

    const int n_nodes = in_sizes[1];                 // N = adj length
    const int ntiles  = (n_nodes + BM - 1) / BM;

    // ws layout: W1h[32768] W1l[32768] W2h[65536] W2l[65536] (shorts)
    //            c1[256] Q[64*256] P[nb*256] (floats)
    short* W1h = (short*)d_ws;
    short* W1l = W1h + 32768;
    short* W2h = W1l + 32768;
    short* W2l = W2h + 65536;
    float* c1  = (float*)(W2l + 65536);
    float* Q   = c1 + HID;
    float* P   = Q + 64 * HID;

    const size_t fixed_bytes = 196608 * sizeof(short) + (HID + 64 * HID) * sizeof(float);
    int nb = 512;
    while (nb > 64 && fixed_bytes + (size_t)nb * HID * sizeof(float) > ws_size)
        nb >>= 1;

    prep_c1<<<HID, 64, 0, stream>>>(x, ip, W_n2e, b_n2e, c1);
    prep_pack<<<384, 256, 0, stream>>>(W_n2e, W_e2e, W1h, W1l, W2h, W2l);
    main_kernel<<<nb, TPB, 0, stream>>>(x, adj, W1h, W1l, W2h, W2l, c1, b_e2e,
                                        P, n_nodes, ntiles);
    tail1<<<64, HID, 0, stream>>>(P, Q, nb / 64);
    tail2<<<1, HID, 0, stream>>>(x, ip, Q, W_e2n, b_e2n, W_out, b_out, out);
}